// Round 6
// baseline (163.017 us; speedup 1.0000x reference)
//
#include <hip/hip_runtime.h>

#define H 256
#define W 256
#define W4 (W / 4)             // 64 float4 per image row
#define OWID 250
#define NIMG 256               // B*D
#define BAND 10                // output rows per wave; 25*10 == 250 exactly
#define NBANDS 25
#define NBLK (NBANDS * NIMG)   // 6400 partials
#define WPB 4                  // waves (images) per workgroup

// ---- horizontal 7-tap via batched cross-lane shuffles ----
// Lane t owns cols 4t..4t+3 and needs cols 4t+4..4t+7 (lane t+1) and
// 4t+8,4t+9 (lane t+2). ISSUE all 20 shuffles before FIN consumes any ->
// one overlapped lgkm chain per row instead of 5 serial ones.
#define HWIN_ISSUE(S, P, B3, BW, CX, CY)      \
    P  = (S.x + S.y) + S.z;                   \
    B3 = __shfl_down(P, 1);                   \
    BW = __shfl_down(S.w, 1);                 \
    CX = __shfl_down(S.x, 2);                 \
    CY = __shfl_down(S.y, 2);

#define HWIN_FIN(S, P, B3, BW, CX, CY, WA)    \
    WA[0] = (P + S.w) + B3;                   \
    WA[1] = WA[0] - S.x + BW;                 \
    WA[2] = WA[1] - S.y + CX;                 \
    WA[3] = WA[2] - S.z + CY;

// R5 lesson: the 7-row register history (56 VGPR) pushed the live set past
// VGPR_Count=96 -> scratch spills (WRITE_SIZE 195 KB) + 25 KB unrolled body.
// This version keeps NO history: the leaving row is RE-READ from L1/L2
// (loaded 7 rows earlier, cache-hot; HBM traffic unchanged). Row loop is
// compact (unroll 3), 4 loads/row prefetched one row ahead.
__global__ __launch_bounds__(256) void ssim_band_kernel(
    const float* __restrict__ X, const float* __restrict__ Y,
    float* __restrict__ partial)
{
    const int lane = threadIdx.x & 63;        // owns cols 4*lane..4*lane+3
    const int wave = threadIdx.x >> 6;        // 0..3 -> image within group
    const int band = blockIdx.x;              // 0..24
    const int img  = blockIdx.y * WPB + wave; // 0..255
    const int r0 = band * BAND;

    const float4* Xp = (const float4*)X + ((size_t)img * H + r0) * W4 + lane;
    const float4* Yp = (const float4*)Y + ((size_t)img * H + r0) * W4 + lane;

    // Running vertical raw sums over the current 7-row window.
    float4 sx, sy, sxx, syy, sxy;

    // ---- init: rows 0..5 (12 independent loads -> one vmcnt wait) ----
    {
        float4 xv = Xp[0], yv = Yp[0];
        sx = xv; sy = yv;
        sxx = make_float4(xv.x * xv.x, xv.y * xv.y, xv.z * xv.z, xv.w * xv.w);
        syy = make_float4(yv.x * yv.x, yv.y * yv.y, yv.z * yv.z, yv.w * yv.w);
        sxy = make_float4(xv.x * yv.x, xv.y * yv.y, xv.z * yv.z, xv.w * yv.w);
        #pragma unroll
        for (int i = 1; i < 6; ++i) {
            float4 a = Xp[i * W4], b = Yp[i * W4];
            sx.x += a.x; sx.y += a.y; sx.z += a.z; sx.w += a.w;
            sy.x += b.x; sy.y += b.y; sy.z += b.z; sy.w += b.w;
            sxx.x = fmaf(a.x, a.x, sxx.x); sxx.y = fmaf(a.y, a.y, sxx.y);
            sxx.z = fmaf(a.z, a.z, sxx.z); sxx.w = fmaf(a.w, a.w, sxx.w);
            syy.x = fmaf(b.x, b.x, syy.x); syy.y = fmaf(b.y, b.y, syy.y);
            syy.z = fmaf(b.z, b.z, syy.z); syy.w = fmaf(b.w, b.w, syy.w);
            sxy.x = fmaf(a.x, b.x, sxy.x); sxy.y = fmaf(a.y, b.y, sxy.y);
            sxy.z = fmaf(a.z, b.z, sxy.z); sxy.w = fmaf(a.w, b.w, sxy.w);
        }
    }

    // SSIM on RAW 7x7 sums (1/49, 1/2401 normalizations cancel in the ratio).
    const float C1N  = 0.2401f;        // 1e-4 * 2401
    const float C2N  = 2.1609f;        // 9e-4 * 2401
    const float COV  = 49.0f / 48.0f;
    const float COV2 = 2.0f * COV;
    float lsum = 0.0f;

    #define SSIM_ROW(wx, wy, wxx, wyy, wxy)                                   \
    {                                                                         \
        _Pragma("unroll")                                                     \
        for (int s = 0; s < 4; ++s) {                                         \
            const float SX = wx[s], SY = wy[s];                               \
            const float t1 = SX * SY;                                         \
            const float t2 = SX * SX;                                         \
            const float t3 = SY * SY;                                         \
            const float A1 = 2.0f * t1 + C1N;                                 \
            const float B1 = (t2 + t3) + C1N;                                 \
            const float A2 = COV2 * (49.0f * wxy[s] - t1) + C2N;              \
            const float B2 = COV * (49.0f * (wxx[s] + wyy[s]) - (t2 + t3)) + C2N; \
            const float S = (A1 * A2) * __builtin_amdgcn_rcpf(B1 * B2);       \
            if (4 * lane + s < OWID) lsum += S;                               \
        }                                                                     \
    }

    #define HWIN_SSIM()                                                       \
    {                                                                         \
        float p0, b30, bw0, cx0, cy0;                                         \
        float p1, b31, bw1, cx1, cy1;                                         \
        float p2, b32, bw2, cx2, cy2;                                         \
        float p3, b33, bw3, cx3, cy3;                                         \
        float p4, b34, bw4, cx4, cy4;                                         \
        HWIN_ISSUE(sx,  p0, b30, bw0, cx0, cy0)                               \
        HWIN_ISSUE(sy,  p1, b31, bw1, cx1, cy1)                               \
        HWIN_ISSUE(sxx, p2, b32, bw2, cx2, cy2)                               \
        HWIN_ISSUE(syy, p3, b33, bw3, cx3, cy3)                               \
        HWIN_ISSUE(sxy, p4, b34, bw4, cx4, cy4)                               \
        float wx[4], wy[4], wxx[4], wyy[4], wxy[4];                           \
        HWIN_FIN(sx,  p0, b30, bw0, cx0, cy0, wx)                             \
        HWIN_FIN(sy,  p1, b31, bw1, cx1, cy1, wy)                             \
        HWIN_FIN(sxx, p2, b32, bw2, cx2, cy2, wxx)                            \
        HWIN_FIN(syy, p3, b33, bw3, cx3, cy3, wyy)                            \
        HWIN_FIN(sxy, p4, b34, bw4, cx4, cy4, wxy)                            \
        SSIM_ROW(wx, wy, wxx, wyy, wxy)                                       \
    }

    // ---- peel j=0: window rows 0..6; prefetch j=1's 4 rows before HWIN ----
    float4 xn = Xp[6 * W4], yn = Yp[6 * W4];
    float4 xnp = Xp[7 * W4], ynp = Yp[7 * W4];  // j=1 new (row 7)
    float4 xop = Xp[0],      yop = Yp[0];       // j=1 old (row 0, L1-hot)
    {
        sx.x += xn.x; sx.y += xn.y; sx.z += xn.z; sx.w += xn.w;
        sy.x += yn.x; sy.y += yn.y; sy.z += yn.z; sy.w += yn.w;
        sxx.x = fmaf(xn.x, xn.x, sxx.x); sxx.y = fmaf(xn.y, xn.y, sxx.y);
        sxx.z = fmaf(xn.z, xn.z, sxx.z); sxx.w = fmaf(xn.w, xn.w, sxx.w);
        syy.x = fmaf(yn.x, yn.x, syy.x); syy.y = fmaf(yn.y, yn.y, syy.y);
        syy.z = fmaf(yn.z, yn.z, syy.z); syy.w = fmaf(yn.w, yn.w, syy.w);
        sxy.x = fmaf(xn.x, yn.x, sxy.x); sxy.y = fmaf(xn.y, yn.y, sxy.y);
        sxy.z = fmaf(xn.z, yn.z, sxy.z); sxy.w = fmaf(xn.w, yn.w, sxy.w);
        HWIN_SSIM()
    }

    // ---- rows j=1..9: compact rolled loop (unroll 3), 1-row prefetch ----
    #pragma unroll 3
    for (int j = 1; j < BAND; ++j) {
        const float4 cxn = xnp, cyn = ynp, cxo = xop, cyo = yop;
        if (j + 1 < BAND) {                  // wave-uniform guard
            xnp = Xp[(j + 7) * W4]; ynp = Yp[(j + 7) * W4];
            xop = Xp[j * W4];       yop = Yp[j * W4];
        }
        // slide: add entering row (j+6), subtract leaving row (j-1)
        sx.x += cxn.x - cxo.x; sx.y += cxn.y - cxo.y;
        sx.z += cxn.z - cxo.z; sx.w += cxn.w - cxo.w;
        sy.x += cyn.x - cyo.x; sy.y += cyn.y - cyo.y;
        sy.z += cyn.z - cyo.z; sy.w += cyn.w - cyo.w;
        sxx.x += cxn.x * cxn.x - cxo.x * cxo.x;
        sxx.y += cxn.y * cxn.y - cxo.y * cxo.y;
        sxx.z += cxn.z * cxn.z - cxo.z * cxo.z;
        sxx.w += cxn.w * cxn.w - cxo.w * cxo.w;
        syy.x += cyn.x * cyn.x - cyo.x * cyo.x;
        syy.y += cyn.y * cyn.y - cyo.y * cyo.y;
        syy.z += cyn.z * cyn.z - cyo.z * cyo.z;
        syy.w += cyn.w * cyn.w - cyo.w * cyo.w;
        sxy.x += cxn.x * cyn.x - cxo.x * cyo.x;
        sxy.y += cxn.y * cyn.y - cxo.y * cyo.y;
        sxy.z += cxn.z * cyn.z - cxo.z * cyo.z;
        sxy.w += cxn.w * cyn.w - cxo.w * cyo.w;
        HWIN_SSIM()
    }

    // Wave reduction -> one partial per wave.
    #pragma unroll
    for (int off = 32; off > 0; off >>= 1)
        lsum += __shfl_down(lsum, off, 64);
    if (lane == 0) partial[img * NBANDS + band] = lsum;
}

__global__ __launch_bounds__(1024) void ssim_reduce_kernel(
    const float* __restrict__ partial, float* __restrict__ out)
{
    const int tid = threadIdx.x;
    double acc = 0.0;
    for (int i = tid; i < NBLK; i += 1024)
        acc += (double)partial[i];
    #pragma unroll
    for (int off = 32; off > 0; off >>= 1)
        acc += __shfl_down(acc, off, 64);
    __shared__ double wsumd[16];
    if ((tid & 63) == 0) wsumd[tid >> 6] = acc;
    __syncthreads();
    if (tid == 0) {
        double total = 0.0;
        #pragma unroll
        for (int i = 0; i < 16; ++i) total += wsumd[i];
        float loss = (float)(1.0 - total / 16000000.0);
        out[0] = loss; out[1] = loss; out[2] = loss; out[3] = loss;
    }
}

extern "C" void kernel_launch(void* const* d_in, const int* in_sizes, int n_in,
                              void* d_out, int out_size, void* d_ws, size_t ws_size,
                              hipStream_t stream) {
    const float* X = (const float*)d_in[0];
    const float* Y = (const float*)d_in[1];
    // d_in[2] is the uniform 7x7 filter (1/49 everywhere) — constant-folded.
    float* out = (float*)d_out;
    float* partial = (float*)d_ws;   // 6400 floats = 25.6 KB

    hipLaunchKernelGGL(ssim_band_kernel, dim3(NBANDS, NIMG / WPB), dim3(256), 0,
                       stream, X, Y, partial);
    hipLaunchKernelGGL(ssim_reduce_kernel, dim3(1), dim3(1024), 0, stream,
                       partial, out);
}